// Round 4
// baseline (1133.990 us; speedup 1.0000x reference)
//
#include <hip/hip_runtime.h>
#include <math.h>

#define N_NODES 100000
#define N_EDGES 1600000
#define M_TOT   (N_EDGES + N_NODES)   // edges + self loops = 1,700,000
#define C_DIM   128
#define NEG_SLOPE 0.2f
#define BN_EPS 1e-5f

#define NBUCK 8
#define BUCK_NODES 12500
#define BUCK_CAP 240000

#define KSTR 136                      // LDS k-stride (bf16 elements): breaks bank alignment
#define BN_BLOCKS 256

typedef short bf16x8 __attribute__((ext_vector_type(8)));
typedef float f32x4 __attribute__((ext_vector_type(4)));

// bf16 <-> fp32 helpers (bit-level, RNE on pack)
static __device__ __forceinline__ unsigned short f2bf(float f) {
    unsigned int b = __float_as_uint(f);
    b += 0x7FFFu + ((b >> 16) & 1u);
    return (unsigned short)(b >> 16);
}
static __device__ __forceinline__ float bf2f(unsigned short u) {
    return __uint_as_float(((unsigned int)u) << 16);
}

// ---------------------------------------------------------------------------
// utility kernels
// ---------------------------------------------------------------------------
__global__ void zero_i32(int* __restrict__ p, int n) {
    int i = blockIdx.x * blockDim.x + threadIdx.x;
    if (i < n) p[i] = 0;
}

// ---------------------------------------------------------------------------
// CSR build, XCD-partitioned bucket sort (unchanged from round 3)
// ---------------------------------------------------------------------------
__global__ __launch_bounds__(256) void bucket_edges(const int* __restrict__ ei,
                                                    int* __restrict__ bucket_next,
                                                    int2* __restrict__ buckets) {
    __shared__ int cnt[NBUCK];
    __shared__ int base[NBUCK];
    int tid = threadIdx.x;
    if (tid < NBUCK) cnt[tid] = 0;
    __syncthreads();
    int m = blockIdx.x * 256 + tid;
    int src = 0, dst = 0, p = 0, myoff = 0;
    bool valid = (m < M_TOT);
    if (valid) {
        if (m < N_EDGES) { src = ei[m]; dst = ei[N_EDGES + m]; }
        else             { src = m - N_EDGES; dst = src; }
        p = dst / BUCK_NODES;
        myoff = atomicAdd(&cnt[p], 1);
    }
    __syncthreads();
    if (tid < NBUCK) base[tid] = (cnt[tid] > 0) ? atomicAdd(&bucket_next[tid], cnt[tid]) : 0;
    __syncthreads();
    if (valid) {
        buckets[(size_t)p * BUCK_CAP + base[p] + myoff] = make_int2(src, dst);
    }
}

__global__ __launch_bounds__(256) void count_deg_b(const int2* __restrict__ buckets,
                                                   const int* __restrict__ bucket_next,
                                                   int* __restrict__ deg) {
    int p = blockIdx.x & 7;
    int chunk = blockIdx.x >> 3;
    int len = bucket_next[p];
    const int2* b = buckets + (size_t)p * BUCK_CAP;
    int stride = (gridDim.x >> 3) * 256;
    for (int i = chunk * 256 + threadIdx.x; i < len; i += stride) {
        atomicAdd(&deg[b[i].y], 1);
    }
}

__global__ __launch_bounds__(256) void scatter_b(const int2* __restrict__ buckets,
                                                 const int* __restrict__ bucket_next,
                                                 int* __restrict__ nextp,
                                                 int* __restrict__ csr_src) {
    int p = blockIdx.x & 7;
    int chunk = blockIdx.x >> 3;
    int len = bucket_next[p];
    const int2* b = buckets + (size_t)p * BUCK_CAP;
    int stride = (gridDim.x >> 3) * 256;
    for (int i = chunk * 256 + threadIdx.x; i < len; i += stride) {
        int2 e = b[i];
        int pos = atomicAdd(&nextp[e.y], 1);
        csr_src[pos] = e.x;
    }
}

// ---------------------------------------------------------------------------
// prefix scan over deg -> row_ptr / nextp
// ---------------------------------------------------------------------------
__global__ __launch_bounds__(256) void block_sums(const int* __restrict__ deg,
                                                  int* __restrict__ partials) {
    __shared__ int lds[256];
    int base = blockIdx.x * 1024;
    int s = 0;
    for (int i = threadIdx.x; i < 1024; i += 256) {
        int idx = base + i;
        if (idx < N_NODES) s += deg[idx];
    }
    lds[threadIdx.x] = s;
    __syncthreads();
    for (int off = 128; off > 0; off >>= 1) {
        if (threadIdx.x < off) lds[threadIdx.x] += lds[threadIdx.x + off];
        __syncthreads();
    }
    if (threadIdx.x == 0) partials[blockIdx.x] = lds[0];
}

// parallel exclusive scan over <=128 partials (one block, 128 threads)
__global__ __launch_bounds__(128) void scan_partials(int* __restrict__ partials, int nb,
                                                     int* __restrict__ row_ptr) {
    __shared__ int lds[128];
    int tid = threadIdx.x;
    int v = (tid < nb) ? partials[tid] : 0;
    lds[tid] = v;
    __syncthreads();
    for (int off = 1; off < 128; off <<= 1) {
        int t = (tid >= off) ? lds[tid - off] : 0;
        __syncthreads();
        lds[tid] += t;
        __syncthreads();
    }
    if (tid < nb) partials[tid] = lds[tid] - v;   // exclusive
    if (tid == 0) row_ptr[N_NODES] = M_TOT;
}

__global__ __launch_bounds__(256) void scan_write(const int* __restrict__ deg,
                                                  const int* __restrict__ partials,
                                                  int* __restrict__ row_ptr,
                                                  int* __restrict__ nextp) {
    __shared__ int lds[256];
    int tid = threadIdx.x;
    int base = blockIdx.x * 1024;
    int i0 = base + tid * 4;
    int d[4];
#pragma unroll
    for (int t = 0; t < 4; ++t)
        d[t] = (i0 + t < N_NODES) ? deg[i0 + t] : 0;
    int tsum = d[0] + d[1] + d[2] + d[3];
    lds[tid] = tsum;
    __syncthreads();
    for (int off = 1; off < 256; off <<= 1) {
        int v = (tid >= off) ? lds[tid - off] : 0;
        __syncthreads();
        lds[tid] += v;
        __syncthreads();
    }
    int excl = lds[tid] - tsum;
    int run = partials[blockIdx.x] + excl;
#pragma unroll
    for (int t = 0; t < 4; ++t) {
        if (i0 + t < N_NODES) {
            row_ptr[i0 + t] = run;
            nextp[i0 + t]   = run;
            run += d[t];
        }
    }
}

// ---------------------------------------------------------------------------
// MFMA bf16 GEMM: H[N,128] = X[N,128(ld)] @ W[128,128], fused s_src/s_dst.
// Tile: 128 rows x 128 cols per 256-thr block; 4 waves x (2 row-frags x
// 8 col-frags) of mfma_f32_16x16x32_bf16, K=128 in 4 steps.
// X staged fp32->bf16 LDS row-major (stride KSTR); W staged transposed
// Wt[n][k] so B-frags read contiguous 16B (ds_read_b128).
// ---------------------------------------------------------------------------
__global__ __launch_bounds__(256) void gemm_attn(
    const float* __restrict__ X, int ldx,
    const float* __restrict__ W,
    const float* __restrict__ a_src, const float* __restrict__ a_dst,
    unsigned short* __restrict__ Hb, float* __restrict__ Ssrc,
    float* __restrict__ Sdst) {
    __shared__ unsigned short Xs[128 * KSTR];   // 34.8 KB
    __shared__ unsigned short Wt[128 * KSTR];   // 34.8 KB
    int tid = threadIdx.x;
    int rbase = blockIdx.x * 128;

    // stage X tile (coalesced dwordx4, cvt to bf16, 8B LDS writes)
    {
        int rl = tid >> 5;            // 0..7
        int c4 = (tid & 31) * 4;
#pragma unroll
        for (int i = 0; i < 16; ++i) {
            int r = rl + i * 8;
            int row = rbase + r;
            if (row >= N_NODES) row = N_NODES - 1;
            float4 v = *(const float4*)&X[(size_t)row * ldx + c4];
            ushort4 o;
            o.x = f2bf(v.x); o.y = f2bf(v.y); o.z = f2bf(v.z); o.w = f2bf(v.w);
            *(ushort4*)&Xs[r * KSTR + c4] = o;
        }
    }
    // stage W transposed: Wt[n][k] = W[k][n]
    {
        int kl = tid >> 5;
        int n4 = (tid & 31) * 4;
#pragma unroll
        for (int i = 0; i < 16; ++i) {
            int k = kl + i * 8;
            float4 v = *(const float4*)&W[k * 128 + n4];
            Wt[(n4 + 0) * KSTR + k] = f2bf(v.x);
            Wt[(n4 + 1) * KSTR + k] = f2bf(v.y);
            Wt[(n4 + 2) * KSTR + k] = f2bf(v.z);
            Wt[(n4 + 3) * KSTR + k] = f2bf(v.w);
        }
    }
    __syncthreads();

    int wave = tid >> 6;
    int lane = tid & 63;
    int q = lane >> 4;       // quad 0..3
    int l15 = lane & 15;
    int wrow = wave * 32;    // wave's row base within tile

    f32x4 acc[2][8] = {};

#pragma unroll
    for (int ks = 0; ks < 4; ++ks) {
        int k0 = ks * 32 + q * 8;
        bf16x8 a0 = *(bf16x8*)&Xs[(wrow + l15) * KSTR + k0];
        bf16x8 a1 = *(bf16x8*)&Xs[(wrow + 16 + l15) * KSTR + k0];
#pragma unroll
        for (int c = 0; c < 8; ++c) {
            bf16x8 b = *(bf16x8*)&Wt[(c * 16 + l15) * KSTR + k0];
            acc[0][c] = __builtin_amdgcn_mfma_f32_16x16x32_bf16(a0, b, acc[0][c], 0, 0, 0);
            acc[1][c] = __builtin_amdgcn_mfma_f32_16x16x32_bf16(a1, b, acc[1][c], 0, 0, 0);
        }
    }

    // epilogue: C/D layout col=lane&15, row=(lane>>4)*4+reg  [m89-verified]
    float avs[8], avd[8];
#pragma unroll
    for (int c = 0; c < 8; ++c) {
        avs[c] = a_src[c * 16 + l15];
        avd[c] = a_dst[c * 16 + l15];
    }
#pragma unroll
    for (int r = 0; r < 2; ++r) {
        float ps[4] = {0, 0, 0, 0}, pd[4] = {0, 0, 0, 0};
#pragma unroll
        for (int g = 0; g < 4; ++g) {
            int row = rbase + wrow + r * 16 + q * 4 + g;
            bool ok = (row < N_NODES);
#pragma unroll
            for (int c = 0; c < 8; ++c) {
                float h = acc[r][c][g];
                if (ok) Hb[(size_t)row * 128 + c * 16 + l15] = f2bf(h);
                ps[g] = fmaf(h, avs[c], ps[g]);
                pd[g] = fmaf(h, avd[c], pd[g]);
            }
        }
#pragma unroll
        for (int g = 0; g < 4; ++g) {
#pragma unroll
            for (int off = 1; off < 16; off <<= 1) {
                ps[g] += __shfl_xor(ps[g], off, 64);
                pd[g] += __shfl_xor(pd[g], off, 64);
            }
        }
        if (l15 == 0) {
#pragma unroll
            for (int g = 0; g < 4; ++g) {
                int row = rbase + wrow + r * 16 + q * 4 + g;
                if (row < N_NODES) {
                    Ssrc[row] = ps[g];
                    Sdst[row] = pd[g];
                }
            }
        }
    }
}

// ---------------------------------------------------------------------------
// Per-node softmax + weighted aggregation (unchanged from round 3)
// ---------------------------------------------------------------------------
__global__ __launch_bounds__(256) void aggregate(
    const unsigned short* __restrict__ Hb, const int* __restrict__ row_ptr,
    const int* __restrict__ csr_src,
    const float* __restrict__ Ssrc, const float* __restrict__ Sdst,
    const float* __restrict__ bias, float* __restrict__ Y) {
    int wave = threadIdx.x >> 6;
    int lane = threadIdx.x & 63;
    int v = blockIdx.x * 4 + wave;
    int start = row_ptr[v];
    int end = row_ptr[v + 1];
    float sdv = Sdst[v];

    float m = -1e30f;
    for (int j = start + lane; j < end; j += 64) {
        float s = Ssrc[csr_src[j]] + sdv;
        s = (s > 0.0f) ? s : NEG_SLOPE * s;
        m = fmaxf(m, s);
    }
#pragma unroll
    for (int off = 32; off >= 1; off >>= 1) m = fmaxf(m, __shfl_xor(m, off, 64));

    float denom = 0.0f, ax = 0.0f, ay = 0.0f;
    int j = start;
    int n4 = start + ((end - start) & ~3);
    for (; j < n4; j += 4) {
        int u0 = csr_src[j];
        int u1 = csr_src[j + 1];
        int u2 = csr_src[j + 2];
        int u3 = csr_src[j + 3];
        float s0 = Ssrc[u0] + sdv;
        float s1 = Ssrc[u1] + sdv;
        float s2 = Ssrc[u2] + sdv;
        float s3 = Ssrc[u3] + sdv;
        ushort2 h0 = *(const ushort2*)&Hb[(size_t)u0 * 128 + lane * 2];
        ushort2 h1 = *(const ushort2*)&Hb[(size_t)u1 * 128 + lane * 2];
        ushort2 h2 = *(const ushort2*)&Hb[(size_t)u2 * 128 + lane * 2];
        ushort2 h3 = *(const ushort2*)&Hb[(size_t)u3 * 128 + lane * 2];
        s0 = (s0 > 0.0f) ? s0 : NEG_SLOPE * s0;
        s1 = (s1 > 0.0f) ? s1 : NEG_SLOPE * s1;
        s2 = (s2 > 0.0f) ? s2 : NEG_SLOPE * s2;
        s3 = (s3 > 0.0f) ? s3 : NEG_SLOPE * s3;
        float w0 = __expf(s0 - m);
        float w1 = __expf(s1 - m);
        float w2 = __expf(s2 - m);
        float w3 = __expf(s3 - m);
        denom += (w0 + w1) + (w2 + w3);
        ax = fmaf(w0, bf2f(h0.x), ax);
        ay = fmaf(w0, bf2f(h0.y), ay);
        ax = fmaf(w1, bf2f(h1.x), ax);
        ay = fmaf(w1, bf2f(h1.y), ay);
        ax = fmaf(w2, bf2f(h2.x), ax);
        ay = fmaf(w2, bf2f(h2.y), ay);
        ax = fmaf(w3, bf2f(h3.x), ax);
        ay = fmaf(w3, bf2f(h3.y), ay);
    }
    for (; j < end; ++j) {
        int u = csr_src[j];
        float s = Ssrc[u] + sdv;
        s = (s > 0.0f) ? s : NEG_SLOPE * s;
        float w = __expf(s - m);
        denom += w;
        ushort2 hv = *(const ushort2*)&Hb[(size_t)u * 128 + lane * 2];
        ax = fmaf(w, bf2f(hv.x), ax);
        ay = fmaf(w, bf2f(hv.y), ay);
    }
    float inv = 1.0f / denom;
    float2 b = *(const float2*)&bias[lane * 2];
    float ox = fmaxf(fmaf(ax, inv, b.x), 0.0f);
    float oy = fmaxf(fmaf(ay, inv, b.y), 0.0f);
    *(float2*)&Y[(size_t)v * 128 + lane * 2] = make_float2(ox, oy);
}

// ---------------------------------------------------------------------------
// BatchNorm: per-block partials (no atomics), then single-block reduce.
// ---------------------------------------------------------------------------
__global__ __launch_bounds__(128) void bn_stats(const float* __restrict__ Y,
                                                float* __restrict__ partial) {
    int c = threadIdx.x;
    float s = 0.0f, q = 0.0f;
    for (int i = blockIdx.x; i < N_NODES; i += BN_BLOCKS) {
        float v = Y[(size_t)i * 128 + c];
        s += v;
        q = fmaf(v, v, q);
    }
    partial[(size_t)blockIdx.x * 256 + c] = s;
    partial[(size_t)blockIdx.x * 256 + 128 + c] = q;
}

__global__ __launch_bounds__(128) void bn_finalize(const float* __restrict__ partial,
                                                   const float* __restrict__ gamma,
                                                   const float* __restrict__ beta,
                                                   float* __restrict__ gb) {
    int c = threadIdx.x;
    float s = 0.0f, q = 0.0f;
    for (int b = 0; b < BN_BLOCKS; ++b) {
        s += partial[(size_t)b * 256 + c];
        q += partial[(size_t)b * 256 + 128 + c];
    }
    const float invN = 1.0f / (float)N_NODES;
    float mu = s * invN;
    float var = q * invN - mu * mu;
    float g = gamma[c] * rsqrtf(var + BN_EPS);
    gb[c] = g;
    gb[128 + c] = beta[c] - mu * g;
}

__global__ __launch_bounds__(256) void bn_apply(const float* __restrict__ Y,
                                                const float* __restrict__ gb,
                                                float* __restrict__ out) {
    int idx = blockIdx.x * blockDim.x + threadIdx.x;
    if (idx >= N_NODES * 32) return;
    int row = idx >> 5;
    int c4 = (idx & 31) * 4;
    float4 v = *(const float4*)&Y[(size_t)row * 128 + c4];
    float4 g = *(const float4*)&gb[c4];
    float4 b = *(const float4*)&gb[128 + c4];
    v.x = fmaf(v.x, g.x, b.x);
    v.y = fmaf(v.y, g.y, b.y);
    v.z = fmaf(v.z, g.z, b.z);
    v.w = fmaf(v.w, g.w, b.w);
    *(float4*)&out[(size_t)row * 384 + c4] = v;
}

// ---------------------------------------------------------------------------
// driver
// ---------------------------------------------------------------------------
extern "C" void kernel_launch(void* const* d_in, const int* in_sizes, int n_in,
                              void* d_out, int out_size, void* d_ws, size_t ws_size,
                              hipStream_t stream) {
    const float* x      = (const float*)d_in[0];
    const int*   ei     = (const int*)d_in[1];   // [2, E] int32
    const float* Wall   = (const float*)d_in[2];
    const float* asrcs  = (const float*)d_in[3];
    const float* adsts  = (const float*)d_in[4];
    const float* biases = (const float*)d_in[5];
    const float* gammas = (const float*)d_in[6];
    const float* betas  = (const float*)d_in[7];
    float* out = (float*)d_out;

    // workspace layout
    unsigned short* Hb = (unsigned short*)d_ws;              // N*128 bf16
    float* Y       = (float*)(Hb + (size_t)N_NODES * 128);   // N*128 fp32
    float* Ssrc    = Y + (size_t)N_NODES * 128;
    float* Sdst    = Ssrc + N_NODES;
    float* bnpart  = Sdst + N_NODES;                         // 256*256
    float* gb      = bnpart + BN_BLOCKS * 256;               // 256
    int* deg       = (int*)(gb + 256);                       // 100000
    int* bucket_next = deg + N_NODES;                        // 8
    int* row_ptr   = bucket_next + NBUCK;                    // 100001
    int* nextp     = row_ptr + (N_NODES + 1);                // 100000
    int* partials  = nextp + N_NODES;                        // 128
    int* csr_src   = partials + 128;                         // 1.7M
    int2* buckets  = (int2*)(csr_src + M_TOT + 2);           // 8*240000 int2

    const int NB_SCAN = (N_NODES + 1023) / 1024;             // 98
    const int NB_EDGE = (M_TOT + 255) / 256;                 // 6641
    const int NB_PART = 2048;

    // ---- CSR build (bucketed) ----
    zero_i32<<<(N_NODES + NBUCK + 255) / 256, 256, 0, stream>>>(deg, N_NODES + NBUCK);
    bucket_edges<<<NB_EDGE, 256, 0, stream>>>(ei, bucket_next, buckets);
    count_deg_b<<<NB_PART, 256, 0, stream>>>(buckets, bucket_next, deg);
    block_sums<<<NB_SCAN, 256, 0, stream>>>(deg, partials);
    scan_partials<<<1, 128, 0, stream>>>(partials, NB_SCAN, row_ptr);
    scan_write<<<NB_SCAN, 256, 0, stream>>>(deg, partials, row_ptr, nextp);
    scatter_b<<<NB_PART, 256, 0, stream>>>(buckets, bucket_next, nextp, csr_src);

    // ---- 3 GAT layers ----
    for (int l = 0; l < 3; ++l) {
        const float* xin = (l == 0) ? x : (out + (size_t)(l - 1) * 128);
        int ldx = (l == 0) ? 128 : 384;
        gemm_attn<<<(N_NODES + 127) / 128, 256, 0, stream>>>(
            xin, ldx, Wall + (size_t)l * 128 * 128,
            asrcs + l * 128, adsts + l * 128, Hb, Ssrc, Sdst);
        aggregate<<<N_NODES / 4, 256, 0, stream>>>(
            Hb, row_ptr, csr_src, Ssrc, Sdst, biases + l * 128, Y);
        bn_stats<<<BN_BLOCKS, 128, 0, stream>>>(Y, bnpart);
        bn_finalize<<<1, 128, 0, stream>>>(bnpart, gammas + l * 128,
                                           betas + l * 128, gb);
        bn_apply<<<(N_NODES * 32 + 255) / 256, 256, 0, stream>>>(
            Y, gb, out + (size_t)l * 128);
    }
}

// Round 5
// 918.262 us; speedup vs baseline: 1.2349x; 1.2349x over previous
//
#include <hip/hip_runtime.h>
#include <math.h>

#define N_NODES 100000
#define N_EDGES 1600000
#define M_TOT   (N_EDGES + N_NODES)   // edges + self loops = 1,700,000
#define C_DIM   128
#define NEG_SLOPE 0.2f
#define BN_EPS 1e-5f

#define NBUCK 8
#define BUCK_NODES 12500
#define BUCK_CAP 240000

#define KSTR 136                      // LDS k-stride (fp16 elements): breaks bank alignment
#define BN_BLOCKS 1024

typedef _Float16 f16x8 __attribute__((ext_vector_type(8)));
typedef float f32x4 __attribute__((ext_vector_type(4)));

// fp16 <-> fp32 helpers (native cvt instructions)
static __device__ __forceinline__ unsigned short f2h(float f) {
    _Float16 h = (_Float16)f;
    unsigned short u;
    __builtin_memcpy(&u, &h, 2);
    return u;
}
static __device__ __forceinline__ float h2f(unsigned short u) {
    _Float16 h;
    __builtin_memcpy(&h, &u, 2);
    return (float)h;
}

// ---------------------------------------------------------------------------
// utility kernels
// ---------------------------------------------------------------------------
__global__ void zero_i32(int* __restrict__ p, int n) {
    int i = blockIdx.x * blockDim.x + threadIdx.x;
    if (i < n) p[i] = 0;
}

// ---------------------------------------------------------------------------
// CSR build, XCD-partitioned bucket sort (unchanged from round 3)
// ---------------------------------------------------------------------------
__global__ __launch_bounds__(256) void bucket_edges(const int* __restrict__ ei,
                                                    int* __restrict__ bucket_next,
                                                    int2* __restrict__ buckets) {
    __shared__ int cnt[NBUCK];
    __shared__ int base[NBUCK];
    int tid = threadIdx.x;
    if (tid < NBUCK) cnt[tid] = 0;
    __syncthreads();
    int m = blockIdx.x * 256 + tid;
    int src = 0, dst = 0, p = 0, myoff = 0;
    bool valid = (m < M_TOT);
    if (valid) {
        if (m < N_EDGES) { src = ei[m]; dst = ei[N_EDGES + m]; }
        else             { src = m - N_EDGES; dst = src; }
        p = dst / BUCK_NODES;
        myoff = atomicAdd(&cnt[p], 1);
    }
    __syncthreads();
    if (tid < NBUCK) base[tid] = (cnt[tid] > 0) ? atomicAdd(&bucket_next[tid], cnt[tid]) : 0;
    __syncthreads();
    if (valid) {
        buckets[(size_t)p * BUCK_CAP + base[p] + myoff] = make_int2(src, dst);
    }
}

__global__ __launch_bounds__(256) void count_deg_b(const int2* __restrict__ buckets,
                                                   const int* __restrict__ bucket_next,
                                                   int* __restrict__ deg) {
    int p = blockIdx.x & 7;
    int chunk = blockIdx.x >> 3;
    int len = bucket_next[p];
    const int2* b = buckets + (size_t)p * BUCK_CAP;
    int stride = (gridDim.x >> 3) * 256;
    for (int i = chunk * 256 + threadIdx.x; i < len; i += stride) {
        atomicAdd(&deg[b[i].y], 1);
    }
}

__global__ __launch_bounds__(256) void scatter_b(const int2* __restrict__ buckets,
                                                 const int* __restrict__ bucket_next,
                                                 int* __restrict__ nextp,
                                                 int* __restrict__ csr_src) {
    int p = blockIdx.x & 7;
    int chunk = blockIdx.x >> 3;
    int len = bucket_next[p];
    const int2* b = buckets + (size_t)p * BUCK_CAP;
    int stride = (gridDim.x >> 3) * 256;
    for (int i = chunk * 256 + threadIdx.x; i < len; i += stride) {
        int2 e = b[i];
        int pos = atomicAdd(&nextp[e.y], 1);
        csr_src[pos] = e.x;
    }
}

// ---------------------------------------------------------------------------
// prefix scan over deg -> row_ptr / nextp
// ---------------------------------------------------------------------------
__global__ __launch_bounds__(256) void block_sums(const int* __restrict__ deg,
                                                  int* __restrict__ partials) {
    __shared__ int lds[256];
    int base = blockIdx.x * 1024;
    int s = 0;
    for (int i = threadIdx.x; i < 1024; i += 256) {
        int idx = base + i;
        if (idx < N_NODES) s += deg[idx];
    }
    lds[threadIdx.x] = s;
    __syncthreads();
    for (int off = 128; off > 0; off >>= 1) {
        if (threadIdx.x < off) lds[threadIdx.x] += lds[threadIdx.x + off];
        __syncthreads();
    }
    if (threadIdx.x == 0) partials[blockIdx.x] = lds[0];
}

__global__ __launch_bounds__(128) void scan_partials(int* __restrict__ partials, int nb,
                                                     int* __restrict__ row_ptr) {
    __shared__ int lds[128];
    int tid = threadIdx.x;
    int v = (tid < nb) ? partials[tid] : 0;
    lds[tid] = v;
    __syncthreads();
    for (int off = 1; off < 128; off <<= 1) {
        int t = (tid >= off) ? lds[tid - off] : 0;
        __syncthreads();
        lds[tid] += t;
        __syncthreads();
    }
    if (tid < nb) partials[tid] = lds[tid] - v;   // exclusive
    if (tid == 0) row_ptr[N_NODES] = M_TOT;
}

__global__ __launch_bounds__(256) void scan_write(const int* __restrict__ deg,
                                                  const int* __restrict__ partials,
                                                  int* __restrict__ row_ptr,
                                                  int* __restrict__ nextp) {
    __shared__ int lds[256];
    int tid = threadIdx.x;
    int base = blockIdx.x * 1024;
    int i0 = base + tid * 4;
    int d[4];
#pragma unroll
    for (int t = 0; t < 4; ++t)
        d[t] = (i0 + t < N_NODES) ? deg[i0 + t] : 0;
    int tsum = d[0] + d[1] + d[2] + d[3];
    lds[tid] = tsum;
    __syncthreads();
    for (int off = 1; off < 256; off <<= 1) {
        int v = (tid >= off) ? lds[tid - off] : 0;
        __syncthreads();
        lds[tid] += v;
        __syncthreads();
    }
    int excl = lds[tid] - tsum;
    int run = partials[blockIdx.x] + excl;
#pragma unroll
    for (int t = 0; t < 4; ++t) {
        if (i0 + t < N_NODES) {
            row_ptr[i0 + t] = run;
            nextp[i0 + t]   = run;
            run += d[t];
        }
    }
}

// ---------------------------------------------------------------------------
// MFMA fp16 GEMM: H[N,128] = X[N,128(ld)] @ W[128,128], fused s_src/s_dst.
// fp16 (not bf16): 3 extra mantissa bits keep absmax well under threshold;
// all values |v|<100 so fp16 range is safe; accumulation fp32.
// Tile: 128 rows x 128 cols per 256-thr block; mfma_f32_16x16x32_f16.
// ---------------------------------------------------------------------------
__global__ __launch_bounds__(256) void gemm_attn(
    const float* __restrict__ X, int ldx,
    const float* __restrict__ W,
    const float* __restrict__ a_src, const float* __restrict__ a_dst,
    unsigned short* __restrict__ Hh, float* __restrict__ Ssrc,
    float* __restrict__ Sdst) {
    __shared__ unsigned short Xs[128 * KSTR];   // 34.8 KB
    __shared__ unsigned short Wt[128 * KSTR];   // 34.8 KB
    int tid = threadIdx.x;
    int rbase = blockIdx.x * 128;

    // stage X tile (coalesced dwordx4, cvt to fp16, 8B LDS writes)
    {
        int rl = tid >> 5;            // 0..7
        int c4 = (tid & 31) * 4;
#pragma unroll
        for (int i = 0; i < 16; ++i) {
            int r = rl + i * 8;
            int row = rbase + r;
            if (row >= N_NODES) row = N_NODES - 1;
            float4 v = *(const float4*)&X[(size_t)row * ldx + c4];
            ushort4 o;
            o.x = f2h(v.x); o.y = f2h(v.y); o.z = f2h(v.z); o.w = f2h(v.w);
            *(ushort4*)&Xs[r * KSTR + c4] = o;
        }
    }
    // stage W transposed: Wt[n][k] = W[k][n]
    {
        int kl = tid >> 5;
        int n4 = (tid & 31) * 4;
#pragma unroll
        for (int i = 0; i < 16; ++i) {
            int k = kl + i * 8;
            float4 v = *(const float4*)&W[k * 128 + n4];
            Wt[(n4 + 0) * KSTR + k] = f2h(v.x);
            Wt[(n4 + 1) * KSTR + k] = f2h(v.y);
            Wt[(n4 + 2) * KSTR + k] = f2h(v.z);
            Wt[(n4 + 3) * KSTR + k] = f2h(v.w);
        }
    }
    __syncthreads();

    int wave = tid >> 6;
    int lane = tid & 63;
    int q = lane >> 4;       // quad 0..3
    int l15 = lane & 15;
    int wrow = wave * 32;    // wave's row base within tile

    f32x4 acc[2][8] = {};

#pragma unroll
    for (int ks = 0; ks < 4; ++ks) {
        int k0 = ks * 32 + q * 8;
        f16x8 a0 = *(f16x8*)&Xs[(wrow + l15) * KSTR + k0];
        f16x8 a1 = *(f16x8*)&Xs[(wrow + 16 + l15) * KSTR + k0];
#pragma unroll
        for (int c = 0; c < 8; ++c) {
            f16x8 b = *(f16x8*)&Wt[(c * 16 + l15) * KSTR + k0];
            acc[0][c] = __builtin_amdgcn_mfma_f32_16x16x32_f16(a0, b, acc[0][c], 0, 0, 0);
            acc[1][c] = __builtin_amdgcn_mfma_f32_16x16x32_f16(a1, b, acc[1][c], 0, 0, 0);
        }
    }

    // epilogue: C/D layout col=lane&15, row=(lane>>4)*4+reg  [m89-verified]
    float avs[8], avd[8];
#pragma unroll
    for (int c = 0; c < 8; ++c) {
        avs[c] = a_src[c * 16 + l15];
        avd[c] = a_dst[c * 16 + l15];
    }
#pragma unroll
    for (int r = 0; r < 2; ++r) {
        float ps[4] = {0, 0, 0, 0}, pd[4] = {0, 0, 0, 0};
#pragma unroll
        for (int g = 0; g < 4; ++g) {
            int row = rbase + wrow + r * 16 + q * 4 + g;
            bool ok = (row < N_NODES);
#pragma unroll
            for (int c = 0; c < 8; ++c) {
                float h = acc[r][c][g];
                if (ok) Hh[(size_t)row * 128 + c * 16 + l15] = f2h(h);
                ps[g] = fmaf(h, avs[c], ps[g]);
                pd[g] = fmaf(h, avd[c], pd[g]);
            }
        }
#pragma unroll
        for (int g = 0; g < 4; ++g) {
#pragma unroll
            for (int off = 1; off < 16; off <<= 1) {
                ps[g] += __shfl_xor(ps[g], off, 64);
                pd[g] += __shfl_xor(pd[g], off, 64);
            }
        }
        if (l15 == 0) {
#pragma unroll
            for (int g = 0; g < 4; ++g) {
                int row = rbase + wrow + r * 16 + q * 4 + g;
                if (row < N_NODES) {
                    Ssrc[row] = ps[g];
                    Sdst[row] = pd[g];
                }
            }
        }
    }
}

// ---------------------------------------------------------------------------
// Per-node softmax + weighted aggregation. One wave per node (64 lanes x 2 ch).
// H gathered in fp16, accumulation fp32.
// ---------------------------------------------------------------------------
__global__ __launch_bounds__(256) void aggregate(
    const unsigned short* __restrict__ Hh, const int* __restrict__ row_ptr,
    const int* __restrict__ csr_src,
    const float* __restrict__ Ssrc, const float* __restrict__ Sdst,
    const float* __restrict__ bias, float* __restrict__ Y) {
    int wave = threadIdx.x >> 6;
    int lane = threadIdx.x & 63;
    int v = blockIdx.x * 4 + wave;
    int start = row_ptr[v];
    int end = row_ptr[v + 1];
    float sdv = Sdst[v];

    float m = -1e30f;
    for (int j = start + lane; j < end; j += 64) {
        float s = Ssrc[csr_src[j]] + sdv;
        s = (s > 0.0f) ? s : NEG_SLOPE * s;
        m = fmaxf(m, s);
    }
#pragma unroll
    for (int off = 32; off >= 1; off >>= 1) m = fmaxf(m, __shfl_xor(m, off, 64));

    float denom = 0.0f, ax = 0.0f, ay = 0.0f;
    int j = start;
    int n4 = start + ((end - start) & ~3);
    for (; j < n4; j += 4) {
        int u0 = csr_src[j];
        int u1 = csr_src[j + 1];
        int u2 = csr_src[j + 2];
        int u3 = csr_src[j + 3];
        float s0 = Ssrc[u0] + sdv;
        float s1 = Ssrc[u1] + sdv;
        float s2 = Ssrc[u2] + sdv;
        float s3 = Ssrc[u3] + sdv;
        ushort2 h0 = *(const ushort2*)&Hh[(size_t)u0 * 128 + lane * 2];
        ushort2 h1 = *(const ushort2*)&Hh[(size_t)u1 * 128 + lane * 2];
        ushort2 h2 = *(const ushort2*)&Hh[(size_t)u2 * 128 + lane * 2];
        ushort2 h3 = *(const ushort2*)&Hh[(size_t)u3 * 128 + lane * 2];
        s0 = (s0 > 0.0f) ? s0 : NEG_SLOPE * s0;
        s1 = (s1 > 0.0f) ? s1 : NEG_SLOPE * s1;
        s2 = (s2 > 0.0f) ? s2 : NEG_SLOPE * s2;
        s3 = (s3 > 0.0f) ? s3 : NEG_SLOPE * s3;
        float w0 = __expf(s0 - m);
        float w1 = __expf(s1 - m);
        float w2 = __expf(s2 - m);
        float w3 = __expf(s3 - m);
        denom += (w0 + w1) + (w2 + w3);
        ax = fmaf(w0, h2f(h0.x), ax);
        ay = fmaf(w0, h2f(h0.y), ay);
        ax = fmaf(w1, h2f(h1.x), ax);
        ay = fmaf(w1, h2f(h1.y), ay);
        ax = fmaf(w2, h2f(h2.x), ax);
        ay = fmaf(w2, h2f(h2.y), ay);
        ax = fmaf(w3, h2f(h3.x), ax);
        ay = fmaf(w3, h2f(h3.y), ay);
    }
    for (; j < end; ++j) {
        int u = csr_src[j];
        float s = Ssrc[u] + sdv;
        s = (s > 0.0f) ? s : NEG_SLOPE * s;
        float w = __expf(s - m);
        denom += w;
        ushort2 hv = *(const ushort2*)&Hh[(size_t)u * 128 + lane * 2];
        ax = fmaf(w, h2f(hv.x), ax);
        ay = fmaf(w, h2f(hv.y), ay);
    }
    float inv = 1.0f / denom;
    float2 b = *(const float2*)&bias[lane * 2];
    float ox = fmaxf(fmaf(ax, inv, b.x), 0.0f);
    float oy = fmaxf(fmaf(ay, inv, b.y), 0.0f);
    *(float2*)&Y[(size_t)v * 128 + lane * 2] = make_float2(ox, oy);
}

// ---------------------------------------------------------------------------
// BatchNorm: 1024 blocks x 256 thr (8 row-lanes x 32 float4 col-groups),
// vectorized loads, LDS tree-reduce over row-lanes, per-block partials.
// ---------------------------------------------------------------------------
__global__ __launch_bounds__(256) void bn_stats(const float* __restrict__ Y,
                                                float* __restrict__ partial) {
    __shared__ float red[256 * 8];    // 8 KB
    int tid = threadIdx.x;
    int rowlane = tid >> 5;           // 0..7
    int cg = tid & 31;                // col-group of 4
    float4 s = make_float4(0, 0, 0, 0);
    float4 qq = make_float4(0, 0, 0, 0);
    for (int i = blockIdx.x * 8 + rowlane; i < N_NODES; i += BN_BLOCKS * 8) {
        float4 v = *(const float4*)&Y[(size_t)i * 128 + cg * 4];
        s.x += v.x; s.y += v.y; s.z += v.z; s.w += v.w;
        qq.x = fmaf(v.x, v.x, qq.x);
        qq.y = fmaf(v.y, v.y, qq.y);
        qq.z = fmaf(v.z, v.z, qq.z);
        qq.w = fmaf(v.w, v.w, qq.w);
    }
    float* r = &red[tid * 8];
    r[0] = s.x; r[1] = s.y; r[2] = s.z; r[3] = s.w;
    r[4] = qq.x; r[5] = qq.y; r[6] = qq.z; r[7] = qq.w;
    __syncthreads();
    for (int off = 4; off > 0; off >>= 1) {
        if (rowlane < off) {
            float* o = &red[(tid + off * 32) * 8];
#pragma unroll
            for (int t = 0; t < 8; ++t) r[t] += o[t];
        }
        __syncthreads();
    }
    if (rowlane == 0) {
        *(float4*)&partial[(size_t)blockIdx.x * 256 + cg * 4] =
            make_float4(r[0], r[1], r[2], r[3]);
        *(float4*)&partial[(size_t)blockIdx.x * 256 + 128 + cg * 4] =
            make_float4(r[4], r[5], r[6], r[7]);
    }
}

__global__ __launch_bounds__(256) void bn_finalize(const float* __restrict__ partial,
                                                   const float* __restrict__ gamma,
                                                   const float* __restrict__ beta,
                                                   float* __restrict__ gb) {
    __shared__ float tot[256];
    int tid = threadIdx.x;
    float acc = 0.0f;
    for (int b = 0; b < BN_BLOCKS; ++b) acc += partial[(size_t)b * 256 + tid];
    tot[tid] = acc;
    __syncthreads();
    if (tid < 128) {
        const float invN = 1.0f / (float)N_NODES;
        float mu = tot[tid] * invN;
        float var = tot[128 + tid] * invN - mu * mu;
        float g = gamma[tid] * rsqrtf(var + BN_EPS);
        gb[tid] = g;
        gb[128 + tid] = beta[tid] - mu * g;
    }
}

__global__ __launch_bounds__(256) void bn_apply(const float* __restrict__ Y,
                                                const float* __restrict__ gb,
                                                float* __restrict__ out) {
    int idx = blockIdx.x * blockDim.x + threadIdx.x;
    if (idx >= N_NODES * 32) return;
    int row = idx >> 5;
    int c4 = (idx & 31) * 4;
    float4 v = *(const float4*)&Y[(size_t)row * 128 + c4];
    float4 g = *(const float4*)&gb[c4];
    float4 b = *(const float4*)&gb[128 + c4];
    v.x = fmaf(v.x, g.x, b.x);
    v.y = fmaf(v.y, g.y, b.y);
    v.z = fmaf(v.z, g.z, b.z);
    v.w = fmaf(v.w, g.w, b.w);
    *(float4*)&out[(size_t)row * 384 + c4] = v;
}

// ---------------------------------------------------------------------------
// driver
// ---------------------------------------------------------------------------
extern "C" void kernel_launch(void* const* d_in, const int* in_sizes, int n_in,
                              void* d_out, int out_size, void* d_ws, size_t ws_size,
                              hipStream_t stream) {
    const float* x      = (const float*)d_in[0];
    const int*   ei     = (const int*)d_in[1];   // [2, E] int32
    const float* Wall   = (const float*)d_in[2];
    const float* asrcs  = (const float*)d_in[3];
    const float* adsts  = (const float*)d_in[4];
    const float* biases = (const float*)d_in[5];
    const float* gammas = (const float*)d_in[6];
    const float* betas  = (const float*)d_in[7];
    float* out = (float*)d_out;

    // workspace layout
    unsigned short* Hh = (unsigned short*)d_ws;              // N*128 fp16
    float* Y       = (float*)(Hh + (size_t)N_NODES * 128);   // N*128 fp32
    float* Ssrc    = Y + (size_t)N_NODES * 128;
    float* Sdst    = Ssrc + N_NODES;
    float* bnpart  = Sdst + N_NODES;                         // 1024*256 = 1MB
    float* gb      = bnpart + BN_BLOCKS * 256;               // 256
    int* deg       = (int*)(gb + 256);                       // 100000
    int* bucket_next = deg + N_NODES;                        // 8
    int* row_ptr   = bucket_next + NBUCK;                    // 100001
    int* nextp     = row_ptr + (N_NODES + 1);                // 100000
    int* partials  = nextp + N_NODES;                        // 128
    int* csr_src   = partials + 128;                         // 1.7M
    int2* buckets  = (int2*)(csr_src + M_TOT + 2);           // 8*240000 int2

    const int NB_SCAN = (N_NODES + 1023) / 1024;             // 98
    const int NB_EDGE = (M_TOT + 255) / 256;                 // 6641
    const int NB_PART = 2048;

    // ---- CSR build (bucketed) ----
    zero_i32<<<(N_NODES + NBUCK + 255) / 256, 256, 0, stream>>>(deg, N_NODES + NBUCK);
    bucket_edges<<<NB_EDGE, 256, 0, stream>>>(ei, bucket_next, buckets);
    count_deg_b<<<NB_PART, 256, 0, stream>>>(buckets, bucket_next, deg);
    block_sums<<<NB_SCAN, 256, 0, stream>>>(deg, partials);
    scan_partials<<<1, 128, 0, stream>>>(partials, NB_SCAN, row_ptr);
    scan_write<<<NB_SCAN, 256, 0, stream>>>(deg, partials, row_ptr, nextp);
    scatter_b<<<NB_PART, 256, 0, stream>>>(buckets, bucket_next, nextp, csr_src);

    // ---- 3 GAT layers ----
    for (int l = 0; l < 3; ++l) {
        const float* xin = (l == 0) ? x : (out + (size_t)(l - 1) * 128);
        int ldx = (l == 0) ? 128 : 384;
        gemm_attn<<<(N_NODES + 127) / 128, 256, 0, stream>>>(
            xin, ldx, Wall + (size_t)l * 128 * 128,
            asrcs + l * 128, adsts + l * 128, Hh, Ssrc, Sdst);
        aggregate<<<N_NODES / 4, 256, 0, stream>>>(
            Hh, row_ptr, csr_src, Ssrc, Sdst, biases + l * 128, Y);
        bn_stats<<<BN_BLOCKS, 256, 0, stream>>>(Y, bnpart);
        bn_finalize<<<1, 256, 0, stream>>>(bnpart, gammas + l * 128,
                                           betas + l * 128, gb);
        bn_apply<<<(N_NODES * 32 + 255) / 256, 256, 0, stream>>>(
            Y, gb, out + (size_t)l * 128);
    }
}

// Round 8
// 878.749 us; speedup vs baseline: 1.2905x; 1.0450x over previous
//
#include <hip/hip_runtime.h>
#include <math.h>

#define N_NODES 100000
#define N_EDGES 1600000
#define M_TOT   (N_EDGES + N_NODES)   // edges + self loops = 1,700,000
#define C_DIM   128
#define NEG_SLOPE 0.2f
#define BN_EPS 1e-5f

#define NBUCK 8
#define BUCK_NODES 12500
#define BUCK_CAP 240000

#define KS2 72                        // LDS k-stride for 64-k split (8 pad)
#define BN_NB 256                     // bn_stats blocks
#define SCAN_NB 98                    // ceil(100000/1024)

typedef _Float16 f16x8 __attribute__((ext_vector_type(8)));
typedef float f32x4 __attribute__((ext_vector_type(4)));

static __device__ __forceinline__ unsigned short f2h(float f) {
    _Float16 h = (_Float16)f;
    unsigned short u;
    __builtin_memcpy(&u, &h, 2);
    return u;
}
static __device__ __forceinline__ float h2f(unsigned short u) {
    _Float16 h;
    __builtin_memcpy(&h, &u, 2);
    return (float)h;
}

// ---------------------------------------------------------------------------
// utility
// ---------------------------------------------------------------------------
__global__ void zero_i32(int* __restrict__ p, int n) {
    int i = blockIdx.x * blockDim.x + threadIdx.x;
    if (i < n) p[i] = 0;
}

// ---------------------------------------------------------------------------
// CSR build, XCD-partitioned bucket sort
// ---------------------------------------------------------------------------
__global__ __launch_bounds__(256) void bucket_edges(const int* __restrict__ ei,
                                                    int* __restrict__ bucket_next,
                                                    int2* __restrict__ buckets) {
    __shared__ int cnt[NBUCK];
    __shared__ int base[NBUCK];
    int tid = threadIdx.x;
    if (tid < NBUCK) cnt[tid] = 0;
    __syncthreads();
    int m = blockIdx.x * 256 + tid;
    int src = 0, dst = 0, p = 0, myoff = 0;
    bool valid = (m < M_TOT);
    if (valid) {
        if (m < N_EDGES) { src = ei[m]; dst = ei[N_EDGES + m]; }
        else             { src = m - N_EDGES; dst = src; }
        p = dst / BUCK_NODES;
        myoff = atomicAdd(&cnt[p], 1);
    }
    __syncthreads();
    if (tid < NBUCK) base[tid] = (cnt[tid] > 0) ? atomicAdd(&bucket_next[tid], cnt[tid]) : 0;
    __syncthreads();
    if (valid) {
        buckets[(size_t)p * BUCK_CAP + base[p] + myoff] = make_int2(src, dst);
    }
}

__global__ __launch_bounds__(256) void count_deg_b(const int2* __restrict__ buckets,
                                                   const int* __restrict__ bucket_next,
                                                   int* __restrict__ deg) {
    int p = blockIdx.x & 7;
    int chunk = blockIdx.x >> 3;
    int len = bucket_next[p];
    const int2* b = buckets + (size_t)p * BUCK_CAP;
    int stride = (gridDim.x >> 3) * 256;
    for (int i = chunk * 256 + threadIdx.x; i < len; i += stride) {
        atomicAdd(&deg[b[i].y], 1);
    }
}

__global__ __launch_bounds__(256) void scatter_b(const int2* __restrict__ buckets,
                                                 const int* __restrict__ bucket_next,
                                                 int* __restrict__ nextp,
                                                 int* __restrict__ csr_src) {
    int p = blockIdx.x & 7;
    int chunk = blockIdx.x >> 3;
    int len = bucket_next[p];
    const int2* b = buckets + (size_t)p * BUCK_CAP;
    int stride = (gridDim.x >> 3) * 256;
    for (int i = chunk * 256 + threadIdx.x; i < len; i += stride) {
        int2 e = b[i];
        int pos = atomicAdd(&nextp[e.y], 1);
        csr_src[pos] = e.x;
    }
}

// ---------------------------------------------------------------------------
// prefix scan over deg -> row_ptr / nextp (separate kernels: kernel-boundary
// visibility; no cross-XCD ticket races)
// ---------------------------------------------------------------------------
__global__ __launch_bounds__(256) void block_sums(const int* __restrict__ deg,
                                                  int* __restrict__ partials) {
    __shared__ int lds[256];
    int base = blockIdx.x * 1024;
    int s = 0;
    for (int i = threadIdx.x; i < 1024; i += 256) {
        int idx = base + i;
        if (idx < N_NODES) s += deg[idx];
    }
    lds[threadIdx.x] = s;
    __syncthreads();
    for (int off = 128; off > 0; off >>= 1) {
        if (threadIdx.x < off) lds[threadIdx.x] += lds[threadIdx.x + off];
        __syncthreads();
    }
    if (threadIdx.x == 0) partials[blockIdx.x] = lds[0];
}

__global__ __launch_bounds__(128) void scan_partials(int* __restrict__ partials, int nb,
                                                     int* __restrict__ row_ptr) {
    __shared__ int lds[128];
    int tid = threadIdx.x;
    int v = (tid < nb) ? partials[tid] : 0;
    lds[tid] = v;
    __syncthreads();
    for (int off = 1; off < 128; off <<= 1) {
        int t = (tid >= off) ? lds[tid - off] : 0;
        __syncthreads();
        lds[tid] += t;
        __syncthreads();
    }
    if (tid < nb) partials[tid] = lds[tid] - v;   // exclusive
    if (tid == 0) row_ptr[N_NODES] = M_TOT;
}

__global__ __launch_bounds__(256) void scan_write(const int* __restrict__ deg,
                                                  const int* __restrict__ partials,
                                                  int* __restrict__ row_ptr,
                                                  int* __restrict__ nextp) {
    __shared__ int lds[256];
    int tid = threadIdx.x;
    int base = blockIdx.x * 1024;
    int i0 = base + tid * 4;
    int d[4];
#pragma unroll
    for (int t = 0; t < 4; ++t)
        d[t] = (i0 + t < N_NODES) ? deg[i0 + t] : 0;
    int tsum = d[0] + d[1] + d[2] + d[3];
    lds[tid] = tsum;
    __syncthreads();
    for (int off = 1; off < 256; off <<= 1) {
        int v = (tid >= off) ? lds[tid - off] : 0;
        __syncthreads();
        lds[tid] += v;
        __syncthreads();
    }
    int excl = lds[tid] - tsum;
    int run = partials[blockIdx.x] + excl;
#pragma unroll
    for (int t = 0; t < 4; ++t) {
        if (i0 + t < N_NODES) {
            row_ptr[i0 + t] = run;
            nextp[i0 + t]   = run;
            run += d[t];
        }
    }
}

// ---------------------------------------------------------------------------
// MFMA fp16 GEMM, K-split staging: two 64-K stages, LDS 36.9 KB -> 3 blk/CU.
// Tile 128x128 per 256-thr block; mfma_f32_16x16x32_f16; fused Ssrc/Sdst.
// ---------------------------------------------------------------------------
__global__ __launch_bounds__(256, 3) void gemm_attn(
    const float* __restrict__ X, int ldx,
    const float* __restrict__ W,
    const float* __restrict__ a_src, const float* __restrict__ a_dst,
    unsigned short* __restrict__ Hh, float* __restrict__ Ssrc,
    float* __restrict__ Sdst) {
    __shared__ unsigned short Xs[128 * KS2];   // 18.4 KB
    __shared__ unsigned short Wt[128 * KS2];   // 18.4 KB
    int tid = threadIdx.x;
    int rbase = blockIdx.x * 128;

    int wave = tid >> 6;
    int lane = tid & 63;
    int q = lane >> 4;
    int l15 = lane & 15;
    int wrow = wave * 32;

    f32x4 acc[2][8] = {};

    for (int kb = 0; kb < 128; kb += 64) {
        __syncthreads();   // protect LDS reuse from previous stage's readers
        // stage X rows 0..127, k-cols kb..kb+63 (fp32->fp16)
        {
            int rl = tid >> 4;            // 0..15
            int cg = (tid & 15) * 4;      // 0,4,..,60
#pragma unroll
            for (int i = 0; i < 8; ++i) {
                int r = rl + i * 16;
                int row = rbase + r;
                if (row >= N_NODES) row = N_NODES - 1;
                float4 v = *(const float4*)&X[(size_t)row * ldx + kb + cg];
                ushort4 o;
                o.x = f2h(v.x); o.y = f2h(v.y); o.z = f2h(v.z); o.w = f2h(v.w);
                *(ushort4*)&Xs[r * KS2 + cg] = o;
            }
        }
        // stage W transposed: Wt[n][kk] = W[kb+kk][n]
        {
            int kl = tid >> 5;            // 0..7
            int n4 = (tid & 31) * 4;
#pragma unroll
            for (int i = 0; i < 8; ++i) {
                int kk = kl + i * 8;
                float4 v = *(const float4*)&W[(kb + kk) * 128 + n4];
                Wt[(n4 + 0) * KS2 + kk] = f2h(v.x);
                Wt[(n4 + 1) * KS2 + kk] = f2h(v.y);
                Wt[(n4 + 2) * KS2 + kk] = f2h(v.z);
                Wt[(n4 + 3) * KS2 + kk] = f2h(v.w);
            }
        }
        __syncthreads();
#pragma unroll
        for (int ks = 0; ks < 64; ks += 32) {
            int k0 = ks + q * 8;
            f16x8 a0 = *(f16x8*)&Xs[(wrow + l15) * KS2 + k0];
            f16x8 a1 = *(f16x8*)&Xs[(wrow + 16 + l15) * KS2 + k0];
#pragma unroll
            for (int c = 0; c < 8; ++c) {
                f16x8 b = *(f16x8*)&Wt[(c * 16 + l15) * KS2 + k0];
                acc[0][c] = __builtin_amdgcn_mfma_f32_16x16x32_f16(a0, b, acc[0][c], 0, 0, 0);
                acc[1][c] = __builtin_amdgcn_mfma_f32_16x16x32_f16(a1, b, acc[1][c], 0, 0, 0);
            }
        }
    }

    // epilogue: C/D layout col=lane&15, row=(lane>>4)*4+reg
    float avs[8], avd[8];
#pragma unroll
    for (int c = 0; c < 8; ++c) {
        avs[c] = a_src[c * 16 + l15];
        avd[c] = a_dst[c * 16 + l15];
    }
#pragma unroll
    for (int r = 0; r < 2; ++r) {
        float ps[4] = {0, 0, 0, 0}, pd[4] = {0, 0, 0, 0};
#pragma unroll
        for (int g = 0; g < 4; ++g) {
            int row = rbase + wrow + r * 16 + q * 4 + g;
            bool ok = (row < N_NODES);
#pragma unroll
            for (int c = 0; c < 8; ++c) {
                float h = acc[r][c][g];
                if (ok) Hh[(size_t)row * 128 + c * 16 + l15] = f2h(h);
                ps[g] = fmaf(h, avs[c], ps[g]);
                pd[g] = fmaf(h, avd[c], pd[g]);
            }
        }
#pragma unroll
        for (int g = 0; g < 4; ++g) {
#pragma unroll
            for (int off = 1; off < 16; off <<= 1) {
                ps[g] += __shfl_xor(ps[g], off, 64);
                pd[g] += __shfl_xor(pd[g], off, 64);
            }
        }
        if (l15 == 0) {
#pragma unroll
            for (int g = 0; g < 4; ++g) {
                int row = rbase + wrow + r * 16 + q * 4 + g;
                if (row < N_NODES) {
                    Ssrc[row] = ps[g];
                    Sdst[row] = pd[g];
                }
            }
        }
    }
}

// ---------------------------------------------------------------------------
// Per-node softmax + weighted aggregation; 8-edge unroll for gather MLP.
// ---------------------------------------------------------------------------
__global__ __launch_bounds__(256) void aggregate(
    const unsigned short* __restrict__ Hh, const int* __restrict__ row_ptr,
    const int* __restrict__ csr_src,
    const float* __restrict__ Ssrc, const float* __restrict__ Sdst,
    const float* __restrict__ bias, float* __restrict__ Y) {
    int wave = threadIdx.x >> 6;
    int lane = threadIdx.x & 63;
    int v = blockIdx.x * 4 + wave;
    int start = row_ptr[v];
    int end = row_ptr[v + 1];
    float sdv = Sdst[v];

    float m = -1e30f;
    for (int j = start + lane; j < end; j += 64) {
        float s = Ssrc[csr_src[j]] + sdv;
        s = (s > 0.0f) ? s : NEG_SLOPE * s;
        m = fmaxf(m, s);
    }
#pragma unroll
    for (int off = 32; off >= 1; off >>= 1) m = fmaxf(m, __shfl_xor(m, off, 64));

    float denom = 0.0f, ax = 0.0f, ay = 0.0f;
    int j = start;
    int n8 = start + ((end - start) & ~7);
    for (; j < n8; j += 8) {
        int u[8];
        float s[8];
        ushort2 h[8];
#pragma unroll
        for (int t = 0; t < 8; ++t) u[t] = csr_src[j + t];
#pragma unroll
        for (int t = 0; t < 8; ++t)
            h[t] = *(const ushort2*)&Hh[(size_t)u[t] * 128 + lane * 2];
#pragma unroll
        for (int t = 0; t < 8; ++t) s[t] = Ssrc[u[t]] + sdv;
#pragma unroll
        for (int t = 0; t < 8; ++t) {
            float sv = (s[t] > 0.0f) ? s[t] : NEG_SLOPE * s[t];
            float w = __expf(sv - m);
            denom += w;
            ax = fmaf(w, h2f(h[t].x), ax);
            ay = fmaf(w, h2f(h[t].y), ay);
        }
    }
    for (; j < end; ++j) {
        int u = csr_src[j];
        float s = Ssrc[u] + sdv;
        s = (s > 0.0f) ? s : NEG_SLOPE * s;
        float w = __expf(s - m);
        denom += w;
        ushort2 hv = *(const ushort2*)&Hh[(size_t)u * 128 + lane * 2];
        ax = fmaf(w, h2f(hv.x), ax);
        ay = fmaf(w, h2f(hv.y), ay);
    }
    float inv = 1.0f / denom;
    float2 b = *(const float2*)&bias[lane * 2];
    float ox = fmaxf(fmaf(ax, inv, b.x), 0.0f);
    float oy = fmaxf(fmaf(ay, inv, b.y), 0.0f);
    *(float2*)&Y[(size_t)v * 128 + lane * 2] = make_float2(ox, oy);
}

// ---------------------------------------------------------------------------
// BatchNorm: per-block partial sums (no atomics, no cross-block reads within
// a kernel); bn_finalize reads partials across a kernel boundary (coherent).
// ---------------------------------------------------------------------------
__global__ __launch_bounds__(256) void bn_stats(const float* __restrict__ Y,
                                                float* __restrict__ partial) {
    __shared__ float red[256 * 8];    // 8 KB
    int tid = threadIdx.x;
    int rowlane = tid >> 5;           // 0..7
    int cg = tid & 31;                // col-group of 4
    float4 s = make_float4(0, 0, 0, 0);
    float4 qq = make_float4(0, 0, 0, 0);
    for (int i = blockIdx.x * 8 + rowlane; i < N_NODES; i += BN_NB * 8) {
        float4 v = *(const float4*)&Y[(size_t)i * 128 + cg * 4];
        s.x += v.x; s.y += v.y; s.z += v.z; s.w += v.w;
        qq.x = fmaf(v.x, v.x, qq.x);
        qq.y = fmaf(v.y, v.y, qq.y);
        qq.z = fmaf(v.z, v.z, qq.z);
        qq.w = fmaf(v.w, v.w, qq.w);
    }
    float* r = &red[tid * 8];
    r[0] = s.x; r[1] = s.y; r[2] = s.z; r[3] = s.w;
    r[4] = qq.x; r[5] = qq.y; r[6] = qq.z; r[7] = qq.w;
    __syncthreads();
    for (int off = 4; off > 0; off >>= 1) {
        if (rowlane < off) {
            float* o = &red[(tid + off * 32) * 8];
#pragma unroll
            for (int t = 0; t < 8; ++t) r[t] += o[t];
        }
        __syncthreads();
    }
    if (rowlane == 0) {
        *(float4*)&partial[(size_t)blockIdx.x * 256 + cg * 4] =
            make_float4(r[0], r[1], r[2], r[3]);
        *(float4*)&partial[(size_t)blockIdx.x * 256 + 128 + cg * 4] =
            make_float4(r[4], r[5], r[6], r[7]);
    }
}

__global__ __launch_bounds__(256) void bn_finalize(const float* __restrict__ partial,
                                                   const float* __restrict__ gamma,
                                                   const float* __restrict__ beta,
                                                   float* __restrict__ gb) {
    __shared__ float tot[256];
    int tid = threadIdx.x;
    float acc = 0.0f;
    for (int b = 0; b < BN_NB; ++b) acc += partial[(size_t)b * 256 + tid];
    tot[tid] = acc;
    __syncthreads();
    if (tid < 128) {
        const float invN = 1.0f / (float)N_NODES;
        float mu = tot[tid] * invN;
        float var = tot[128 + tid] * invN - mu * mu;
        float g = gamma[tid] * rsqrtf(var + BN_EPS);
        gb[tid] = g;
        gb[128 + tid] = beta[tid] - mu * g;
    }
}

__global__ __launch_bounds__(256) void bn_apply(const float* __restrict__ Y,
                                                const float* __restrict__ gb,
                                                float* __restrict__ out) {
    int idx = blockIdx.x * blockDim.x + threadIdx.x;
    if (idx >= N_NODES * 32) return;
    int row = idx >> 5;
    int c4 = (idx & 31) * 4;
    float4 v = *(const float4*)&Y[(size_t)row * 128 + c4];
    float4 g = *(const float4*)&gb[c4];
    float4 b = *(const float4*)&gb[128 + c4];
    v.x = fmaf(v.x, g.x, b.x);
    v.y = fmaf(v.y, g.y, b.y);
    v.z = fmaf(v.z, g.z, b.z);
    v.w = fmaf(v.w, g.w, b.w);
    *(float4*)&out[(size_t)row * 384 + c4] = v;
}

// ---------------------------------------------------------------------------
// driver
// ---------------------------------------------------------------------------
extern "C" void kernel_launch(void* const* d_in, const int* in_sizes, int n_in,
                              void* d_out, int out_size, void* d_ws, size_t ws_size,
                              hipStream_t stream) {
    const float* x      = (const float*)d_in[0];
    const int*   ei     = (const int*)d_in[1];   // [2, E] int32
    const float* Wall   = (const float*)d_in[2];
    const float* asrcs  = (const float*)d_in[3];
    const float* adsts  = (const float*)d_in[4];
    const float* biases = (const float*)d_in[5];
    const float* gammas = (const float*)d_in[6];
    const float* betas  = (const float*)d_in[7];
    float* out = (float*)d_out;

    // workspace layout
    unsigned short* Hh = (unsigned short*)d_ws;              // N*128 fp16
    float* Y       = (float*)(Hh + (size_t)N_NODES * 128);   // N*128 fp32
    float* Ssrc    = Y + (size_t)N_NODES * 128;
    float* Sdst    = Ssrc + N_NODES;
    float* bnpart  = Sdst + N_NODES;                         // 256*256
    float* gb      = bnpart + BN_NB * 256;                   // 256
    // ---- zero zone (contiguous) ----
    int* deg       = (int*)(gb + 256);                       // 100000
    int* bucket_next = deg + N_NODES;                        // 8
    // ---- end zero zone ----
    int* row_ptr   = bucket_next + NBUCK;                    // 100001
    int* nextp     = row_ptr + (N_NODES + 1);                // 100000
    int* partials  = nextp + N_NODES;                        // 128
    int* csr_src   = partials + 128;                         // 1.7M
    int2* buckets  = (int2*)(csr_src + M_TOT + 2);           // 8*240000 int2

    const int ZERO_CNT = N_NODES + NBUCK;
    const int NB_EDGE = (M_TOT + 255) / 256;                 // 6641
    const int NB_PART = 2048;

    // ---- CSR build (bucketed) ----
    zero_i32<<<(ZERO_CNT + 255) / 256, 256, 0, stream>>>(deg, ZERO_CNT);
    bucket_edges<<<NB_EDGE, 256, 0, stream>>>(ei, bucket_next, buckets);
    count_deg_b<<<NB_PART, 256, 0, stream>>>(buckets, bucket_next, deg);
    block_sums<<<SCAN_NB, 256, 0, stream>>>(deg, partials);
    scan_partials<<<1, 128, 0, stream>>>(partials, SCAN_NB, row_ptr);
    scan_write<<<SCAN_NB, 256, 0, stream>>>(deg, partials, row_ptr, nextp);
    scatter_b<<<NB_PART, 256, 0, stream>>>(buckets, bucket_next, nextp, csr_src);

    // ---- 3 GAT layers ----
    for (int l = 0; l < 3; ++l) {
        const float* xin = (l == 0) ? x : (out + (size_t)(l - 1) * 128);
        int ldx = (l == 0) ? 128 : 384;
        gemm_attn<<<(N_NODES + 127) / 128, 256, 0, stream>>>(
            xin, ldx, Wall + (size_t)l * 128 * 128,
            asrcs + l * 128, adsts + l * 128, Hh, Ssrc, Sdst);
        aggregate<<<N_NODES / 4, 256, 0, stream>>>(
            Hh, row_ptr, csr_src, Ssrc, Sdst, biases + l * 128, Y);
        bn_stats<<<BN_NB, 256, 0, stream>>>(Y, bnpart);
        bn_finalize<<<1, 256, 0, stream>>>(bnpart, gammas + l * 128,
                                           betas + l * 128, gb);
        bn_apply<<<(N_NODES * 32 + 255) / 256, 256, 0, stream>>>(
            Y, gb, out + (size_t)l * 128);
    }
}